// Round 8
// baseline (488.856 us; speedup 1.0000x reference)
//
#include <hip/hip_runtime.h>
#include <math.h>

// Problem constants (B=4, H=16, S=4096, D=64)
#define BH 64
#define SEQ 4096
#define DIM 64
#define CHUNK 32
#define NCHUNK (SEQ / CHUNK)      // 128 chunks per bh
#define NCH_TOT (BH * NCHUNK)     // 8192 chunks total
#define CPB 8                     // chunks per block (4 waves x 2)
#define NBLK (NCH_TOT / CPB)      // 1024 blocks
#define BPB (NCHUNK / CPB)        // 16 blocks per bh
#define TPB 256

__device__ __forceinline__ float fast_rcp(float x)  { return __builtin_amdgcn_rcpf(x); }
__device__ __forceinline__ float fast_rsqrt(float x){ return __builtin_amdgcn_rsqf(x); }
__device__ __forceinline__ float fast_sigmoid(float x) {
    return fast_rcp(1.0f + __expf(-x));
}
__device__ __forceinline__ float swiglu(float v) { return v * v * fast_sigmoid(v); }

// 16-lane xor-tree reduce (within the d-group; lane = g*16 + h layout)
__device__ __forceinline__ float red16(float x) {
    x += __shfl_xor(x, 1);
    x += __shfl_xor(x, 2);
    x += __shfl_xor(x, 4);
    x += __shfl_xor(x, 8);
    return x;
}

// ---------------------------------------------------------------------------
// Per-row scan step (verified in rounds 5/6). All indices compile-time in the
// unrolled caller => registers only. Two calls per j0 (chunks A,B) = 2x ILP.
// ---------------------------------------------------------------------------
__device__ __forceinline__ void scan_step(const float4* __restrict__ q4,
                                          const float4* __restrict__ k4,
                                          const float4* __restrict__ v4,
                                          float4* __restrict__ o4,
                                          float (&cb)[4],
                                          int idx, int g,
                                          int up16, int up32, int src3) {
    float4 v = v4[idx];
    float4 q = q4[idx];
    float4 k = k4[idx];

    // r = ||Q|| + ||K|| + 1  (independent of the scan chain -> free ILP)
    float q2 = red16(q.x*q.x + q.y*q.y + q.z*q.z + q.w*q.w);
    float k2 = red16(k.x*k.x + k.y*k.y + k.z*k.z + k.w*k.w);
    float r  = sqrtf(q2) + sqrtf(k2) + 1.0f;

    float s0 = swiglu(v.x);
    float s1 = swiglu(v.y);
    float s2v = swiglu(v.z);
    float s3 = swiglu(v.w);

    // inclusive scan over the 4 row-slot groups (element-wise per d)
    float t0 = __shfl(s0, up16); s0 += (g >= 1) ? t0 : 0.f;
    float t1 = __shfl(s1, up16); s1 += (g >= 1) ? t1 : 0.f;
    float t2 = __shfl(s2v, up16); s2v += (g >= 1) ? t2 : 0.f;
    float t3 = __shfl(s3, up16); s3 += (g >= 1) ? t3 : 0.f;

    float u0 = __shfl(s0, up32); s0 += (g >= 2) ? u0 : 0.f;
    float u1 = __shfl(s1, up32); s1 += (g >= 2) ? u1 : 0.f;
    float u2 = __shfl(s2v, up32); s2v += (g >= 2) ? u2 : 0.f;
    float u3 = __shfl(s3, up32); s3 += (g >= 2) ? u3 : 0.f;

    float w0 = __shfl(s0, src3);   // full 4-row sums (group 3)
    float w1 = __shfl(s1, src3);
    float w2 = __shfl(s2v, src3);
    float w3 = __shfl(s3, src3);

    float c0 = cb[0] + s0;  cb[0] += w0;
    float c1 = cb[1] + s1;  cb[1] += w1;
    float c2 = cb[2] + s2v; cb[2] += w2;
    float c3 = cb[3] + s3;  cb[3] += w3;

    float cs = red16(c0*c0 + c1*c1 + c2*c2 + c3*c3);
    float rms_c = fast_rsqrt(cs * (1.0f / 64.0f) + 1e-5f);
    float s = rms_c * fast_rcp(r);

    float m0 = c0 * s; float o0 = v.x * (1.0f + m0 * fast_sigmoid(m0));
    float m1 = c1 * s; float o1 = v.y * (1.0f + m1 * fast_sigmoid(m1));
    float m2 = c2 * s; float o2 = v.z * (1.0f + m2 * fast_sigmoid(m2));
    float m3 = c3 * s; float o3 = v.w * (1.0f + m3 * fast_sigmoid(m3));

    float os = red16(o0*o0 + o1*o1 + o2*o2 + o3*o3);
    float rms_o = fast_rsqrt(os * (1.0f / 64.0f) + 1e-5f);
    float4 outv = {o0 * rms_o, o1 * rms_o, o2 * rms_o, o3 * rms_o};
    o4[idx] = outv;
}

// ---------------------------------------------------------------------------
// Single-pass decoupled-lookback kernel.
//   vbid via atomicAdd ticket => any running block's predecessors hold earlier
//   tickets (resident or finished) => spin is deadlock-free regardless of HW
//   dispatch order (rocPRIM/CUB argument, G16-safe).
//   Liveness: a block publishes status=1 BEFORE its own lookback spin, and the
//   spin only needs status[j]!=0 (phase A + publish contain no waits) =>
//   every spin is on a wait-free producer => guaranteed progress.
//   Publish: payload stores -> __threadfence (release) -> atomicExch flag.
//   Consume: atomicAdd(flag,0) spin -> __threadfence (acquire) -> payload load.
//   (Fence pattern numerically validated on this chip in round 4.)
// Phase A: per-chunk swiglu sums (V read). Wave 0: block aggregate publish +
// lookback over <=15 same-bh predecessors. Phase B: dual-chunk interleaved
// scan (Q,K,V read, O write) with carries from LDS + lookback exclusive.
// ---------------------------------------------------------------------------
__global__ __launch_bounds__(TPB, 4) void k_fused_lb(const float* __restrict__ Q,
                                                     const float* __restrict__ K,
                                                     const float* __restrict__ V,
                                                     float* __restrict__ O,
                                                     int* __restrict__ ticket,
                                                     int* __restrict__ status,
                                                     float* __restrict__ agg,
                                                     float* __restrict__ inc) {
    __shared__ int vbid_s;
    __shared__ float cagg[CPB][DIM];   // per-chunk aggregates (d-indexed)
    __shared__ float bexcl[DIM];       // block-exclusive prefix from lookback

    if (threadIdx.x == 0) vbid_s = atomicAdd(ticket, 1);
    __syncthreads();
    const int b    = vbid_s;           // virtual block id = work assignment
    const int bib  = b & (BPB - 1);    // index within its bh
    const int wave = threadIdx.x >> 6;
    const int lane = threadIdx.x & 63;
    const int g = lane >> 4, h = lane & 15;

    const int cA = b * CPB + 2 * wave;           // this wave's chunk pair
    const size_t baseA = (size_t)cA * (CHUNK * DIM);
    const size_t baseB = baseA + (CHUNK * DIM);
    const float4* vA4 = (const float4*)(V + baseA);
    const float4* vB4 = (const float4*)(V + baseB);

    // ---------------- Phase A: per-chunk swiglu sums ----------------
    float aA0=0.f,aA1=0.f,aA2=0.f,aA3=0.f, aB0=0.f,aB1=0.f,aB2=0.f,aB3=0.f;
#pragma unroll
    for (int j0 = 0; j0 < CHUNK; j0 += 4) {
        const int idx = (j0 + g) * 16 + h;
        float4 va = vA4[idx];
        float4 vb = vB4[idx];
        aA0 += swiglu(va.x); aA1 += swiglu(va.y);
        aA2 += swiglu(va.z); aA3 += swiglu(va.w);
        aB0 += swiglu(vb.x); aB1 += swiglu(vb.y);
        aB2 += swiglu(vb.z); aB3 += swiglu(vb.w);
    }
#pragma unroll
    for (int m = 16; m < 64; m <<= 1) {           // reduce across the 4 groups
        aA0 += __shfl_xor(aA0, m); aA1 += __shfl_xor(aA1, m);
        aA2 += __shfl_xor(aA2, m); aA3 += __shfl_xor(aA3, m);
        aB0 += __shfl_xor(aB0, m); aB1 += __shfl_xor(aB1, m);
        aB2 += __shfl_xor(aB2, m); aB3 += __shfl_xor(aB3, m);
    }
    if (g == 0) {
        float4 sa = {aA0, aA1, aA2, aA3};
        float4 sb = {aB0, aB1, aB2, aB3};
        ((float4*)cagg[2 * wave])[h]     = sa;
        ((float4*)cagg[2 * wave + 1])[h] = sb;
    }
    __syncthreads();

    // ---------------- publish + decoupled lookback (wave 0 only) ----------
    if (wave == 0) {
        float bagg = 0.f;                          // block aggregate, d = lane
#pragma unroll
        for (int i = 0; i < CPB; ++i) bagg += cagg[i][lane];
        agg[(size_t)b * DIM + lane] = bagg;
        if (bib == 0) {
            inc[(size_t)b * DIM + lane] = bagg;
            __threadfence();                       // release payload
            if (lane == 0) atomicExch(&status[b], 2);
            bexcl[lane] = 0.f;
        } else {
            __threadfence();                       // release agg
            if (lane == 0) atomicExch(&status[b], 1);
            float ex = 0.f;
            int j = b - 1;
            for (;;) {
                int st = 0;
                if (lane == 0) {
                    while ((st = atomicAdd(&status[j], 0)) == 0)
                        __builtin_amdgcn_s_sleep(1);
                }
                st = __shfl(st, 0);
                __threadfence();                   // acquire j's payload
                if (st == 2) { ex += inc[(size_t)j * DIM + lane]; break; }
                ex += agg[(size_t)j * DIM + lane];
                --j;                               // terminates at bib==0 (status 2)
            }
            inc[(size_t)b * DIM + lane] = ex + bagg;
            __threadfence();                       // release inclusive
            if (lane == 0) atomicExch(&status[b], 2);
            bexcl[lane] = ex;
        }
    }
    __syncthreads();

    // ---------------- Phase B: dual-chunk interleaved scan ----------------
    float4 e0 = ((const float4*)bexcl)[h];
    float cbA[4] = {e0.x, e0.y, e0.z, e0.w};
    for (int i = 0; i < 2 * wave; ++i) {           // intra-block chunk prefix
        float4 t = ((const float4*)cagg[i])[h];
        cbA[0] += t.x; cbA[1] += t.y; cbA[2] += t.z; cbA[3] += t.w;
    }
    float4 tA = ((const float4*)cagg[2 * wave])[h];
    float cbB[4] = {cbA[0] + tA.x, cbA[1] + tA.y, cbA[2] + tA.z, cbA[3] + tA.w};

    const float4* qA4 = (const float4*)(Q + baseA);
    const float4* kA4 = (const float4*)(K + baseA);
    float4*       oA4 = (float4*)(O + baseA);
    const float4* qB4 = (const float4*)(Q + baseB);
    const float4* kB4 = (const float4*)(K + baseB);
    float4*       oB4 = (float4*)(O + baseB);

    const int up16 = (lane + 48) & 63;   // lane-16 with wrap (masked for g<1)
    const int up32 = (lane + 32) & 63;   // lane-32 with wrap (masked for g<2)
    const int src3 = 48 + h;             // group-3 lane with same h

#pragma unroll
    for (int j0 = 0; j0 < CHUNK; j0 += 4) {
        const int idx = (j0 + g) * 16 + h;
        scan_step(qA4, kA4, vA4, oA4, cbA, idx, g, up16, up32, src3);
        scan_step(qB4, kB4, vB4, oB4, cbB, idx, g, up16, up32, src3);
    }
}

// ---------------------------------------------------------------------------
extern "C" void kernel_launch(void* const* d_in, const int* in_sizes, int n_in,
                              void* d_out, int out_size, void* d_ws, size_t ws_size,
                              hipStream_t stream) {
    const float* Q = (const float*)d_in[0];
    const float* K = (const float*)d_in[1];
    const float* V = (const float*)d_in[2];
    float* O = (float*)d_out;

    // ws layout: [0,4K)=status[1024], [4K,4K+4)=ticket, [8K,...)=agg,inc payloads
    int*   status = (int*)d_ws;
    int*   ticket = status + NBLK;
    float* agg    = (float*)((char*)d_ws + 8192);
    float* inc    = agg + (size_t)NBLK * DIM;      // +256 KB

    hipMemsetAsync(d_ws, 0, 8192, stream);         // re-arm ticket + flags
    k_fused_lb<<<NBLK, TPB, 0, stream>>>(Q, K, V, O, ticket, status, agg, inc);
}